// Round 1
// baseline (18678.604 us; speedup 1.0000x reference)
//
#include <hip/hip_runtime.h>

#define E_TOTAL 160000
#define NN 20000
#define NGRAPH 64

// ---------------- generic f32 GEMM: C[M,N] = act(A[M,*lda] @ B[Kb,N] + bias) ----------------
// A has padded leading dim lda (multiple of 16 >= Kb), padded cols must be zero.
// N must be a multiple of 128 here (all our N are 256/512/1024).
template <int RELU>
__global__ __launch_bounds__(256) void gemm_f32(
    int M, int N, int Kpad, int Kb,
    const float* __restrict__ A, int lda,
    const float* __restrict__ B,
    float* __restrict__ C, int ldc,
    const float* __restrict__ bias)
{
    __shared__ float As[16][132];
    __shared__ float Bs[16][132];
    const int tid = threadIdx.x;
    const int bm = blockIdx.y * 128;
    const int bn = blockIdx.x * 128;
    const int tx = tid & 15, ty = tid >> 4;

    float acc[8][8];
#pragma unroll
    for (int i = 0; i < 8; ++i)
#pragma unroll
        for (int j = 0; j < 8; ++j) acc[i][j] = 0.f;

    const int ar = tid >> 2, ac = (tid & 3) << 2;   // A staging: row, col4
    const int br = tid >> 5, bc = (tid & 31) << 2;  // B staging: krow, col4

    for (int k0 = 0; k0 < Kpad; k0 += 16) {
#pragma unroll
        for (int h = 0; h < 2; ++h) {
            int row = ar + h * 64;
            int gr = bm + row;
            float4 v = make_float4(0.f, 0.f, 0.f, 0.f);
            if (gr < M) v = *(const float4*)(A + (size_t)gr * lda + k0 + ac);
            As[ac + 0][row] = v.x; As[ac + 1][row] = v.y;
            As[ac + 2][row] = v.z; As[ac + 3][row] = v.w;
        }
#pragma unroll
        for (int h = 0; h < 2; ++h) {
            int kr = k0 + br + h * 8;
            float4 v = make_float4(0.f, 0.f, 0.f, 0.f);
            if (kr < Kb) v = *(const float4*)(B + (size_t)kr * N + bn + bc);
            *(float4*)&Bs[br + h * 8][bc] = v;
        }
        __syncthreads();
#pragma unroll
        for (int k = 0; k < 16; ++k) {
            float4 a0 = *(const float4*)&As[k][ty * 4];
            float4 a1 = *(const float4*)&As[k][64 + ty * 4];
            float4 b0 = *(const float4*)&Bs[k][tx * 4];
            float4 b1 = *(const float4*)&Bs[k][64 + tx * 4];
            float a[8] = {a0.x, a0.y, a0.z, a0.w, a1.x, a1.y, a1.z, a1.w};
            float b[8] = {b0.x, b0.y, b0.z, b0.w, b1.x, b1.y, b1.z, b1.w};
#pragma unroll
            for (int i = 0; i < 8; ++i)
#pragma unroll
                for (int j = 0; j < 8; ++j) acc[i][j] = fmaf(a[i], b[j], acc[i][j]);
        }
        __syncthreads();
    }

#pragma unroll
    for (int i = 0; i < 8; ++i) {
        int r = bm + ((i < 4) ? (ty * 4 + i) : (64 + ty * 4 + i - 4));
        if (r >= M) continue;
#pragma unroll
        for (int jh = 0; jh < 2; ++jh) {
            int c = bn + jh * 64 + tx * 4;
            float4 o;
            o.x = acc[i][jh * 4 + 0] + bias[c + 0];
            o.y = acc[i][jh * 4 + 1] + bias[c + 1];
            o.z = acc[i][jh * 4 + 2] + bias[c + 2];
            o.w = acc[i][jh * 4 + 3] + bias[c + 3];
            if (RELU) {
                o.x = fmaxf(o.x, 0.f); o.y = fmaxf(o.y, 0.f);
                o.z = fmaxf(o.z, 0.f); o.w = fmaxf(o.w, 0.f);
            }
            *(float4*)(C + (size_t)r * ldc + c) = o;
        }
    }
}

// ---------------- gather / scatter kernels ----------------

__global__ void k_gather_feat(int e0, int Ce,
                              const float* __restrict__ x,
                              const float* __restrict__ eattr,
                              const float* __restrict__ u2,
                              const int* __restrict__ ei,
                              const int* __restrict__ batch,
                              float* __restrict__ feat)
{
    int t = blockIdx.x * 256 + threadIdx.x;
    if (t >= Ce * 288) return;
    int i = t / 288, j = t - i * 288;
    int e = e0 + i;
    float v;
    if (j < 9) {
        v = x[ei[e] * 9 + j];
    } else if (j < 18) {
        v = x[ei[E_TOTAL + e] * 9 + (j - 9)];
    } else if (j == 18) {
        v = eattr[e];
    } else if (j < 275) {
        v = u2[batch[ei[e]] * 256 + (j - 19)];
    } else {
        v = 0.f;
    }
    feat[(size_t)i * 288 + j] = v;
}

__global__ void k_gather_hfeat(int e0, int Ce,
                               const float* __restrict__ x,
                               const float* __restrict__ e_out, // [Ce,512]
                               const int* __restrict__ ei,
                               float* __restrict__ hf)
{
    int t = blockIdx.x * 256 + threadIdx.x;
    if (t >= Ce * 528) return;
    int i = t / 528, j = t - i * 528;
    float v;
    if (j < 9) {
        v = x[ei[E_TOTAL + e0 + i] * 9 + j];
    } else if (j < 521) {
        v = e_out[(size_t)i * 512 + (j - 9)];
    } else {
        v = 0.f;
    }
    hf[(size_t)i * 528 + j] = v;
}

__global__ void k_scatter(int e0, int Ce,
                          const float* __restrict__ h2, // [Ce,512]
                          const int* __restrict__ ei,
                          float* __restrict__ ssum)
{
    int t = blockIdx.x * 256 + threadIdx.x;
    if (t >= Ce * 512) return;
    int i = t >> 9, j = t & 511;
    int r = ei[e0 + i];
    atomicAdd(ssum + (size_t)r * 512 + j, h2[(size_t)i * 512 + j]);
}

__global__ void k_cnt(const int* __restrict__ ei, float* __restrict__ cnt)
{
    int t = blockIdx.x * 256 + threadIdx.x;
    if (t < E_TOTAL) atomicAdd(cnt + ei[t], 1.0f);
}

__global__ void k_gather_zfeat(const float* __restrict__ x,
                               const float* __restrict__ ssum,
                               const float* __restrict__ cnt,
                               const float* __restrict__ u2,
                               const int* __restrict__ batch,
                               float* __restrict__ zf)
{
    int t = blockIdx.x * 256 + threadIdx.x;
    if (t >= NN * 784) return;
    int n = t / 784, j = t - n * 784;
    float v;
    if (j < 9) {
        v = x[n * 9 + j];
    } else if (j < 521) {
        v = ssum[(size_t)n * 512 + (j - 9)] / fmaxf(cnt[n], 1.f);
    } else if (j < 777) {
        v = u2[batch[n] * 256 + (j - 521)];
    } else {
        v = 0.f;
    }
    zf[(size_t)n * 784 + j] = v;
}

__global__ void k_final(const float* __restrict__ z1,
                        const float* __restrict__ W, // [512]
                        const float* __restrict__ b,
                        float* __restrict__ out)
{
    int gt = blockIdx.x * 256 + threadIdx.x;
    int row = gt >> 6;
    int lane = threadIdx.x & 63;
    if (row >= NN) return;
    float s = 0.f;
#pragma unroll
    for (int c = lane; c < 512; c += 64) s += z1[(size_t)row * 512 + c] * W[c];
#pragma unroll
    for (int off = 32; off; off >>= 1) s += __shfl_down(s, off);
    if (lane == 0) out[row] = s + b[0];
}

// ---------------- launch ----------------

extern "C" void kernel_launch(void* const* d_in, const int* in_sizes, int n_in,
                              void* d_out, int out_size, void* d_ws, size_t ws_size,
                              hipStream_t stream)
{
    const float* x     = (const float*)d_in[0];
    const float* eattr = (const float*)d_in[1];
    const float* u     = (const float*)d_in[2];
    const int*   ei    = (const int*)d_in[3];
    const int*   batch = (const int*)d_in[4];
    const float* Wsel  = (const float*)d_in[5];
    const float* bsel  = (const float*)d_in[6];
    const float* eW1 = (const float*)d_in[7],  * eb1 = (const float*)d_in[8];
    const float* eW2 = (const float*)d_in[9],  * eb2 = (const float*)d_in[10];
    const float* eW3 = (const float*)d_in[11], * eb3 = (const float*)d_in[12];
    const float* eW4 = (const float*)d_in[13], * eb4 = (const float*)d_in[14];
    const float* eW5 = (const float*)d_in[15], * eb5 = (const float*)d_in[16];
    const float* n1W1 = (const float*)d_in[17], * n1b1 = (const float*)d_in[18];
    const float* n1W2 = (const float*)d_in[19], * n1b2 = (const float*)d_in[20];
    const float* n2W1 = (const float*)d_in[21], * n2b1 = (const float*)d_in[22];
    const float* n2W2 = (const float*)d_in[23], * n2b2 = (const float*)d_in[24];
    float* out = (float*)d_out;

    char* ws = (char*)d_ws;
    size_t off = 0;
    auto alloc = [&](size_t nfloats) {
        float* p = (float*)(ws + off);
        off += nfloats * sizeof(float);
        return p;
    };
    float* u2   = alloc((size_t)NGRAPH * 256);
    float* ssum = alloc((size_t)NN * 512);
    float* cnt  = alloc(NN);
    size_t fixed = off;

    // chunk region (reused later for zfeat/z1)
    // per-edge floats: feat 288 + buf1 1024 + buf2 1024 = 2336
    long long availf = (long long)(ws_size - fixed) / 4;
    int C = (int)(availf / 2336);
    C = (C / 128) * 128;
    if (C > E_TOTAL) C = E_TOTAL;
    if (C < 128) C = 128;

    float* featc = (float*)(ws + fixed);
    float* buf1  = featc + (size_t)C * 288;
    float* buf2  = buf1 + (size_t)C * 1024;
    float* zfeat = (float*)(ws + fixed);
    float* z1    = zfeat + (size_t)NN * 784;

    // zero ssum + cnt (contiguous)
    hipMemsetAsync(ssum, 0, ((size_t)NN * 512 + NN) * sizeof(float), stream);

    // u2 = u @ Wsel + bsel   [64,256]
    gemm_f32<0><<<dim3(256 / 128, 1), 256, 0, stream>>>(
        NGRAPH, 256, 4096, 4096, u, 4096, Wsel, u2, 256, bsel);

    // counts (per destination node over row index)
    k_cnt<<<(E_TOTAL + 255) / 256, 256, 0, stream>>>(ei, cnt);

    for (int e0 = 0; e0 < E_TOTAL; e0 += C) {
        int Ce = E_TOTAL - e0 < C ? E_TOTAL - e0 : C;
        int gy = (Ce + 127) / 128;

        k_gather_feat<<<(Ce * 288 + 255) / 256, 256, 0, stream>>>(
            e0, Ce, x, eattr, u2, ei, batch, featc);

        gemm_f32<1><<<dim3(8, gy), 256, 0, stream>>>(
            Ce, 1024, 288, 275, featc, 288, eW1, buf1, 1024, eb1);
        gemm_f32<1><<<dim3(8, gy), 256, 0, stream>>>(
            Ce, 1024, 1024, 1024, buf1, 1024, eW2, buf2, 1024, eb2);
        gemm_f32<1><<<dim3(8, gy), 256, 0, stream>>>(
            Ce, 1024, 1024, 1024, buf2, 1024, eW3, buf1, 1024, eb3);
        gemm_f32<1><<<dim3(8, gy), 256, 0, stream>>>(
            Ce, 1024, 1024, 1024, buf1, 1024, eW4, buf2, 1024, eb4);
        gemm_f32<0><<<dim3(4, gy), 256, 0, stream>>>(
            Ce, 512, 1024, 1024, buf2, 1024, eW5, buf1, 512, eb5); // e -> buf1

        k_gather_hfeat<<<(Ce * 528 + 255) / 256, 256, 0, stream>>>(
            e0, Ce, x, buf1, ei, buf2); // hfeat -> buf2 [Ce,528]

        gemm_f32<1><<<dim3(4, gy), 256, 0, stream>>>(
            Ce, 512, 528, 521, buf2, 528, n1W1, buf1, 512, n1b1); // h1 -> buf1
        gemm_f32<1><<<dim3(4, gy), 256, 0, stream>>>(
            Ce, 512, 512, 512, buf1, 512, n1W2, buf2, 512, n1b2); // h2 -> buf2

        k_scatter<<<(Ce * 512 + 255) / 256, 256, 0, stream>>>(
            e0, Ce, buf2, ei, ssum);
    }

    // readout
    k_gather_zfeat<<<(NN * 784 + 255) / 256, 256, 0, stream>>>(
        x, ssum, cnt, u2, batch, zfeat);
    gemm_f32<1><<<dim3(4, (NN + 127) / 128), 256, 0, stream>>>(
        NN, 512, 784, 777, zfeat, 784, n2W1, z1, 512, n2b1);
    k_final<<<(NN * 64 + 255) / 256, 256, 0, stream>>>(z1, n2W2, n2b2, out);
}

// Round 2
// 3129.971 us; speedup vs baseline: 5.9677x; 5.9677x over previous
//
#include <hip/hip_runtime.h>

typedef _Float16 f16;
typedef __attribute__((ext_vector_type(8))) _Float16 f16x8;
typedef __attribute__((ext_vector_type(4))) float f32x4;

#define E_TOTAL 160000
#define NN 20000
#define NGRAPH 64

__device__ __forceinline__ void gl_lds16(const void* g, void* l) {
    __builtin_amdgcn_global_load_lds((const __attribute__((address_space(1))) void*)g,
                                     (__attribute__((address_space(3))) void*)l, 16, 0, 0);
}

// ---------------- fp16 MFMA GEMM: C[M,N] = act(A[M,lda] @ Bt[N,K]^T + bias) ----------------
// K multiple of 64, N multiple of 128. A rows beyond M must be readable (alloc rounded up).
// m97 structure: 128x128 tile, BK=64, global_load_lds w16, XOR-swizzled LDS (G4 fix).
template <int RELU>
__global__ __launch_bounds__(256, 2) void hgemm(
    int M, int N, int K,
    const f16* __restrict__ A, int lda,
    const f16* __restrict__ Bt,     // [N, K] row-major (B transposed), zero-padded
    f16* __restrict__ C, int ldc,
    const float* __restrict__ bias)
{
    __shared__ __align__(16) char Ash[16384];
    __shared__ __align__(16) char Bsh[16384];
    const int tid  = threadIdx.x;
    const int lane = tid & 63;
    const int w    = tid >> 6;
    const int bm = blockIdx.y * 128;
    const int bn = blockIdx.x * 128;
    const int wm = (w >> 1) * 64;
    const int wn = (w & 1) * 64;
    const int fr = lane & 15;
    const int kq = lane >> 4;

    const char* Ab = (const char*)A;
    const char* Bb = (const char*)Bt;
    const size_t lda2 = (size_t)lda * 2;
    const size_t ldb2 = (size_t)K * 2;

    f32x4 acc[4][4] = {};

    int srow[4], scb[4];
#pragma unroll
    for (int h = 0; h < 4; ++h) {
        int cch = w * 4 + h;
        int L = cch * 1024 + lane * 16;
        int row = L >> 7;
        srow[h] = row;
        scb[h] = (L & 127) ^ ((row & 7) << 4);   // pre-swizzled global source (m173 pattern)
    }

    for (int k0 = 0; k0 < K; k0 += 64) {
        __syncthreads();   // WAR: previous tile's reads done before overwrite
#pragma unroll
        for (int h = 0; h < 4; ++h) {
            int cch = w * 4 + h;
            gl_lds16(Ab + (size_t)(bm + srow[h]) * lda2 + (size_t)k0 * 2 + scb[h], Ash + cch * 1024);
            gl_lds16(Bb + (size_t)(bn + srow[h]) * ldb2 + (size_t)k0 * 2 + scb[h], Bsh + cch * 1024);
        }
        __syncthreads();   // compiler drains vmcnt(0) here
#pragma unroll
        for (int kk = 0; kk < 2; ++kk) {
            const int cb = (kk * 32 + kq * 8) * 2;
            f16x8 av[4], bv[4];
#pragma unroll
            for (int m = 0; m < 4; ++m) {
                int r = wm + m * 16 + fr;
                av[m] = *(const f16x8*)(Ash + r * 128 + (cb ^ ((r & 7) << 4)));
            }
#pragma unroll
            for (int n = 0; n < 4; ++n) {
                int r = wn + n * 16 + fr;
                bv[n] = *(const f16x8*)(Bsh + r * 128 + (cb ^ ((r & 7) << 4)));
            }
#pragma unroll
            for (int m = 0; m < 4; ++m)
#pragma unroll
                for (int n = 0; n < 4; ++n)
                    acc[m][n] = __builtin_amdgcn_mfma_f32_16x16x32_f16(av[m], bv[n], acc[m][n], 0, 0, 0);
        }
    }

    // C/D layout: col = lane&15, row = (lane>>4)*4 + reg (m89-verified)
#pragma unroll
    for (int m = 0; m < 4; ++m) {
        int r0 = bm + wm + m * 16 + kq * 4;
#pragma unroll
        for (int n = 0; n < 4; ++n) {
            int col = bn + wn + n * 16 + fr;
            float bz = bias[col];
#pragma unroll
            for (int r = 0; r < 4; ++r) {
                int grow = r0 + r;
                if (grow < M) {
                    float v = acc[m][n][r] + bz;
                    if (RELU) v = fmaxf(v, 0.f);
                    C[(size_t)grow * ldc + col] = (f16)v;
                }
            }
        }
    }
}

// ---------------- weight transpose + fp16 convert: W[K,N] f32 -> Wt[N,Kp] fp16 ----------------
__global__ void k_wt(const float* __restrict__ W, f16* __restrict__ Wt, int K, int N, int Kp)
{
    size_t t = (size_t)blockIdx.x * 256 + threadIdx.x;
    if (t >= (size_t)N * Kp) return;
    int n = (int)(t / Kp), k = (int)(t % Kp);
    Wt[t] = (k < K) ? (f16)W[(size_t)k * N + n] : (f16)0.f;
}

// ---------------- u2 = u @ Wsel + bsel   [64,4096]x[4096,256] ----------------
__global__ void k_u2(const float* __restrict__ u, const float* __restrict__ Wsel,
                     const float* __restrict__ bsel, float* __restrict__ u2)
{
    __shared__ float us[4096];
    int g = blockIdx.x;
    for (int i = threadIdx.x; i < 4096; i += 256) us[i] = u[(size_t)g * 4096 + i];
    __syncthreads();
    int n = threadIdx.x;
    float acc = bsel[n];
#pragma unroll 8
    for (int k = 0; k < 4096; ++k) acc = fmaf(us[k], Wsel[(size_t)k * 256 + n], acc);
    u2[g * 256 + n] = acc;
}

// ---------------- gathers / scatter ----------------

__global__ void k_gather_feat(int e0, int Ce,
                              const float* __restrict__ x, const float* __restrict__ eattr,
                              const float* __restrict__ u2, const int* __restrict__ ei,
                              const int* __restrict__ batch, f16* __restrict__ feat)
{
    size_t t = (size_t)blockIdx.x * 256 + threadIdx.x;
    if (t >= (size_t)Ce * 320) return;
    int i = (int)(t / 320), j = (int)(t % 320);
    int e = e0 + i;
    float v = 0.f;
    if (j < 9)        v = x[ei[e] * 9 + j];
    else if (j < 18)  v = x[ei[E_TOTAL + e] * 9 + (j - 9)];
    else if (j == 18) v = eattr[e];
    else if (j < 275) v = u2[batch[ei[e]] * 256 + (j - 19)];
    feat[t] = (f16)v;
}

__global__ void k_gather_hfeat(int e0, int Ce,
                               const float* __restrict__ x, const f16* __restrict__ e_out,
                               const int* __restrict__ ei, f16* __restrict__ hf)
{
    size_t t = (size_t)blockIdx.x * 256 + threadIdx.x;
    if (t >= (size_t)Ce * 576) return;
    int i = (int)(t / 576), j = (int)(t % 576);
    f16 v = (f16)0.f;
    if (j < 9)        v = (f16)x[ei[E_TOTAL + e0 + i] * 9 + j];
    else if (j < 521) v = e_out[(size_t)i * 512 + (j - 9)];
    hf[t] = v;
}

__global__ void k_scatter(int e0, int Ce, const f16* __restrict__ h2,
                          const int* __restrict__ ei, float* __restrict__ ssum)
{
    size_t t = (size_t)blockIdx.x * 256 + threadIdx.x;
    if (t >= (size_t)Ce * 512) return;
    int i = (int)(t >> 9), j = (int)(t & 511);
    atomicAdd(ssum + (size_t)ei[e0 + i] * 512 + j, (float)h2[t]);
}

__global__ void k_cnt(const int* __restrict__ ei, float* __restrict__ cnt)
{
    int t = blockIdx.x * 256 + threadIdx.x;
    if (t < E_TOTAL) atomicAdd(cnt + ei[t], 1.0f);
}

__global__ void k_gather_zfeat(const float* __restrict__ x, const float* __restrict__ ssum,
                               const float* __restrict__ cnt, const float* __restrict__ u2,
                               const int* __restrict__ batch, f16* __restrict__ zf)
{
    size_t t = (size_t)blockIdx.x * 256 + threadIdx.x;
    if (t >= (size_t)NN * 832) return;
    int n = (int)(t / 832), j = (int)(t % 832);
    float v = 0.f;
    if (j < 9)        v = x[n * 9 + j];
    else if (j < 521) v = ssum[(size_t)n * 512 + (j - 9)] / fmaxf(cnt[n], 1.f);
    else if (j < 777) v = u2[batch[n] * 256 + (j - 521)];
    zf[t] = (f16)v;
}

__global__ void k_final(const f16* __restrict__ z1, const float* __restrict__ W,
                        const float* __restrict__ b, float* __restrict__ out)
{
    int gt = blockIdx.x * 256 + threadIdx.x;
    int row = gt >> 6;
    int lane = threadIdx.x & 63;
    if (row >= NN) return;
    float s = 0.f;
#pragma unroll
    for (int c = lane; c < 512; c += 64) s += (float)z1[(size_t)row * 512 + c] * W[c];
#pragma unroll
    for (int off = 32; off; off >>= 1) s += __shfl_down(s, off);
    if (lane == 0) out[row] = s + b[0];
}

// ---------------- launch ----------------

extern "C" void kernel_launch(void* const* d_in, const int* in_sizes, int n_in,
                              void* d_out, int out_size, void* d_ws, size_t ws_size,
                              hipStream_t stream)
{
    const float* x     = (const float*)d_in[0];
    const float* eattr = (const float*)d_in[1];
    const float* u     = (const float*)d_in[2];
    const int*   ei    = (const int*)d_in[3];
    const int*   batch = (const int*)d_in[4];
    const float* Wsel  = (const float*)d_in[5];
    const float* bsel  = (const float*)d_in[6];
    const float* eW1 = (const float*)d_in[7],  * eb1 = (const float*)d_in[8];
    const float* eW2 = (const float*)d_in[9],  * eb2 = (const float*)d_in[10];
    const float* eW3 = (const float*)d_in[11], * eb3 = (const float*)d_in[12];
    const float* eW4 = (const float*)d_in[13], * eb4 = (const float*)d_in[14];
    const float* eW5 = (const float*)d_in[15], * eb5 = (const float*)d_in[16];
    const float* n1W1 = (const float*)d_in[17], * n1b1 = (const float*)d_in[18];
    const float* n1W2 = (const float*)d_in[19], * n1b2 = (const float*)d_in[20];
    const float* n2W1 = (const float*)d_in[21], * n2b1 = (const float*)d_in[22];
    const float* n2W2 = (const float*)d_in[23], * n2b2 = (const float*)d_in[24];
    float* out = (float*)d_out;

    char* ws = (char*)d_ws;
    size_t off = 0;
    auto alc = [&](size_t bytes) { char* p = ws + off; off += (bytes + 255) & ~(size_t)255; return p; };

    float* u2   = (float*)alc((size_t)NGRAPH * 256 * 4);
    float* ssum = (float*)alc((size_t)NN * 512 * 4);
    float* cnt  = (float*)alc((size_t)NN * 4);
    f16* eW1t  = (f16*)alc((size_t)1024 * 320 * 2);
    f16* eW2t  = (f16*)alc((size_t)1024 * 1024 * 2);
    f16* eW3t  = (f16*)alc((size_t)1024 * 1024 * 2);
    f16* eW4t  = (f16*)alc((size_t)1024 * 1024 * 2);
    f16* eW5t  = (f16*)alc((size_t)512 * 1024 * 2);
    f16* n1W1t = (f16*)alc((size_t)512 * 576 * 2);
    f16* n1W2t = (f16*)alc((size_t)512 * 512 * 2);
    f16* n2W1t = (f16*)alc((size_t)512 * 832 * 2);
    size_t fixed = off;

    // chunk sizing: per-edge fp16 elems = feat 320 + buf1 1024 + buf2 1024
    size_t per_edge = (320 + 1024 + 1024) * 2;
    size_t avail = ws_size > fixed ? ws_size - fixed : 0;
    long long Cll = (long long)(avail / per_edge);
    int C = (int)((Cll / 128) * 128);
    if (C > E_TOTAL) C = E_TOTAL;   // 160000 is a multiple of 128
    size_t need_ro = ((size_t)20096 * 832 + (size_t)20096 * 512) * 2;  // zfeat + z1 (reuse region)
    int minC = (int)(((need_ro + per_edge - 1) / per_edge + 127) / 128 * 128);
    if (C < minC) C = minC;

    f16* featc = (f16*)(ws + fixed);
    f16* buf1  = featc + (size_t)C * 320;
    f16* buf2  = buf1 + (size_t)C * 1024;
    f16* zfeat = (f16*)(ws + fixed);
    f16* z1    = zfeat + (size_t)20096 * 832;

    // zero ssum..cnt (contiguous block)
    size_t zlen = (size_t)((char*)cnt - (char*)ssum) + (size_t)NN * 4;
    hipMemsetAsync(ssum, 0, zlen, stream);

    // weights -> fp16 transposed
    auto wt = [&](const float* W, f16* Wt, int K, int N, int Kp) {
        size_t tot = (size_t)N * Kp;
        k_wt<<<(unsigned)((tot + 255) / 256), 256, 0, stream>>>(W, Wt, K, N, Kp);
    };
    wt(eW1, eW1t, 275, 1024, 320);
    wt(eW2, eW2t, 1024, 1024, 1024);
    wt(eW3, eW3t, 1024, 1024, 1024);
    wt(eW4, eW4t, 1024, 1024, 1024);
    wt(eW5, eW5t, 1024, 512, 1024);
    wt(n1W1, n1W1t, 521, 512, 576);
    wt(n1W2, n1W2t, 512, 512, 512);
    wt(n2W1, n2W1t, 777, 512, 832);

    k_u2<<<NGRAPH, 256, 0, stream>>>(u, Wsel, bsel, u2);
    k_cnt<<<(E_TOTAL + 255) / 256, 256, 0, stream>>>(ei, cnt);

    for (int e0 = 0; e0 < E_TOTAL; e0 += C) {
        int Ce = E_TOTAL - e0 < C ? E_TOTAL - e0 : C;
        int gy = (Ce + 127) / 128;

        k_gather_feat<<<(unsigned)(((size_t)Ce * 320 + 255) / 256), 256, 0, stream>>>(
            e0, Ce, x, eattr, u2, ei, batch, featc);

        hgemm<1><<<dim3(8, gy), 256, 0, stream>>>(Ce, 1024, 320,  featc, 320,  eW1t, buf1, 1024, eb1);
        hgemm<1><<<dim3(8, gy), 256, 0, stream>>>(Ce, 1024, 1024, buf1,  1024, eW2t, buf2, 1024, eb2);
        hgemm<1><<<dim3(8, gy), 256, 0, stream>>>(Ce, 1024, 1024, buf2,  1024, eW3t, buf1, 1024, eb3);
        hgemm<1><<<dim3(8, gy), 256, 0, stream>>>(Ce, 1024, 1024, buf1,  1024, eW4t, buf2, 1024, eb4);
        hgemm<0><<<dim3(4, gy), 256, 0, stream>>>(Ce, 512,  1024, buf2,  1024, eW5t, buf1, 512,  eb5);

        k_gather_hfeat<<<(unsigned)(((size_t)Ce * 576 + 255) / 256), 256, 0, stream>>>(
            e0, Ce, x, buf1, ei, buf2);

        hgemm<1><<<dim3(4, gy), 256, 0, stream>>>(Ce, 512, 576, buf2, 576, n1W1t, buf1, 512, n1b1);
        hgemm<1><<<dim3(4, gy), 256, 0, stream>>>(Ce, 512, 512, buf1, 512, n1W2t, buf2, 512, n1b2);

        k_scatter<<<(unsigned)(((size_t)Ce * 512 + 255) / 256), 256, 0, stream>>>(
            e0, Ce, buf2, ei, ssum);
    }

    // readout
    k_gather_zfeat<<<(unsigned)(((size_t)NN * 832 + 255) / 256), 256, 0, stream>>>(
        x, ssum, cnt, u2, batch, zfeat);
    hgemm<1><<<dim3(4, (NN + 127) / 128), 256, 0, stream>>>(NN, 512, 832, zfeat, 832, n2W1t, z1, 512, n2b1);
    k_final<<<(NN * 64 + 255) / 256, 256, 0, stream>>>(z1, n2W2, n2b2, out);
}

// Round 3
// 2588.400 us; speedup vs baseline: 7.2163x; 1.2092x over previous
//
#include <hip/hip_runtime.h>

typedef _Float16 f16;
typedef __attribute__((ext_vector_type(8))) _Float16 f16x8;
typedef __attribute__((ext_vector_type(4))) float f32x4;

#define E_TOTAL 160000
#define NN 20000
#define NGRAPH 64

__device__ __forceinline__ void gl_lds16(const void* g, void* l) {
    __builtin_amdgcn_global_load_lds((const __attribute__((address_space(1))) void*)g,
                                     (__attribute__((address_space(3))) void*)l, 16, 0, 0);
}

// ---------------- fp16 MFMA GEMM: C[M,N] = act(A[M,lda] @ Bt[N,K]^T + bias [+aux]) ------------
// K mult of 64, N mult of 128. A rows up to ceil(M/128)*128 must be readable.
// AUXU: += utab[uidx[row]*N + col]  (f16 table, 64 rows)
// AUXX: += dot(x9[xi(row)*9 .. +9], W9[q*N + col])  (rank-9 fused concat part; xi=xidx[row] or row)
template <int RELU, int AUXU, int AUXX>
__global__ __launch_bounds__(256, 2) void hgemm(
    int M, int N, int K,
    const f16* __restrict__ A, int lda,
    const f16* __restrict__ Bt,
    f16* __restrict__ C, int ldc,
    const float* __restrict__ bias,
    const f16* __restrict__ utab, const int* __restrict__ uidx,
    const float* __restrict__ x9, const int* __restrict__ xidx, const float* __restrict__ W9)
{
    __shared__ __align__(16) char Ash[16384];
    __shared__ __align__(16) char Bsh[16384];
    __shared__ float Ws9[AUXX ? 1152 : 1];   // 9 x 128
    const int tid  = threadIdx.x;
    const int lane = tid & 63;
    const int w    = tid >> 6;
    const int bm = blockIdx.y * 128;
    const int bn = blockIdx.x * 128;
    const int wm = (w >> 1) * 64;
    const int wn = (w & 1) * 64;
    const int fr = lane & 15;
    const int kq = lane >> 4;

    const char* Ab = (const char*)A;
    const char* Bb = (const char*)Bt;
    const size_t lda2 = (size_t)lda * 2;
    const size_t ldb2 = (size_t)K * 2;

    f32x4 acc[4][4] = {};

    int srow[4], scb[4];
#pragma unroll
    for (int h = 0; h < 4; ++h) {
        int cch = w * 4 + h;
        int L = cch * 1024 + lane * 16;
        int row = L >> 7;
        srow[h] = row;
        scb[h] = (L & 127) ^ ((row & 7) << 4);   // pre-swizzled global source
    }

    for (int k0 = 0; k0 < K; k0 += 64) {
        __syncthreads();
#pragma unroll
        for (int h = 0; h < 4; ++h) {
            int cch = w * 4 + h;
            gl_lds16(Ab + (size_t)(bm + srow[h]) * lda2 + (size_t)k0 * 2 + scb[h], Ash + cch * 1024);
            gl_lds16(Bb + (size_t)(bn + srow[h]) * ldb2 + (size_t)k0 * 2 + scb[h], Bsh + cch * 1024);
        }
        __syncthreads();
#pragma unroll
        for (int kk = 0; kk < 2; ++kk) {
            const int cb = (kk * 32 + kq * 8) * 2;
            f16x8 av[4], bv[4];
#pragma unroll
            for (int m = 0; m < 4; ++m) {
                int r = wm + m * 16 + fr;
                av[m] = *(const f16x8*)(Ash + r * 128 + (cb ^ ((r & 7) << 4)));
            }
#pragma unroll
            for (int n = 0; n < 4; ++n) {
                int r = wn + n * 16 + fr;
                bv[n] = *(const f16x8*)(Bsh + r * 128 + (cb ^ ((r & 7) << 4)));
            }
#pragma unroll
            for (int m = 0; m < 4; ++m)
#pragma unroll
                for (int n = 0; n < 4; ++n)
                    acc[m][n] = __builtin_amdgcn_mfma_f32_16x16x32_f16(av[m], bv[n], acc[m][n], 0, 0, 0);
        }
    }

    if (AUXX) {
        for (int t = tid; t < 9 * 128; t += 256)
            Ws9[t] = W9[(size_t)(t >> 7) * N + bn + (t & 127)];
        __syncthreads();
    }

    // C/D layout: col = lane&15, row = (lane>>4)*4 + reg
#pragma unroll
    for (int m = 0; m < 4; ++m) {
        int r0 = bm + wm + m * 16 + kq * 4;
#pragma unroll
        for (int r = 0; r < 4; ++r) {
            int grow = r0 + r;
            if (grow >= M) continue;
            int ub = 0;
            if (AUXU) ub = uidx[grow];
            float xv[9];
            if (AUXX) {
                int xi = xidx ? xidx[grow] : grow;
#pragma unroll
                for (int q = 0; q < 9; ++q) xv[q] = x9[(size_t)xi * 9 + q];
            }
#pragma unroll
            for (int n = 0; n < 4; ++n) {
                int lcol = wn + n * 16 + fr;
                int col = bn + lcol;
                float v = acc[m][n][r] + bias[col];
                if (AUXU) v += (float)utab[(size_t)ub * N + col];
                if (AUXX) {
                    float s = 0.f;
#pragma unroll
                    for (int q = 0; q < 9; ++q) s = fmaf(xv[q], Ws9[q * 128 + lcol], s);
                    v += s;
                }
                if (RELU) v = fmaxf(v, 0.f);
                C[(size_t)grow * ldc + col] = (f16)v;
            }
        }
    }
}

// ---- weight slice transpose: Wt[n][k] = W[(r0+k)*N + n], k<Ksub, pad to Kp with 0 ----
__global__ void k_wt(const float* __restrict__ W, f16* __restrict__ Wt,
                     int r0, int Ksub, int N, int Kp)
{
    size_t t = (size_t)blockIdx.x * 256 + threadIdx.x;
    if (t >= (size_t)N * Kp) return;
    int n = (int)(t / Kp), k = (int)(t % Kp);
    Wt[t] = (k < Ksub) ? (f16)W[(size_t)(r0 + k) * N + n] : (f16)0.f;
}

// ---- u2h = f16(u @ Wsel + bsel)  [64,4096]x[4096,256], split-K over 4 parts ----
__global__ __launch_bounds__(256) void k_u2(const float* __restrict__ u,
                                            const float* __restrict__ Wsel,
                                            const float* __restrict__ bsel,
                                            f16* __restrict__ u2h)
{
    __shared__ float us[4096];
    __shared__ float red[4][64];
    const int g = blockIdx.y;
    const int c0 = blockIdx.x * 64;
    const int col = threadIdx.x & 63;
    const int kp = threadIdx.x >> 6;
    for (int i = threadIdx.x; i < 4096; i += 256) us[i] = u[(size_t)g * 4096 + i];
    __syncthreads();
    float acc = 0.f;
    for (int k = kp * 1024; k < kp * 1024 + 1024; ++k)
        acc = fmaf(us[k], Wsel[(size_t)k * 256 + c0 + col], acc);
    red[kp][col] = acc;
    __syncthreads();
    if (kp == 0) {
        float v = red[0][col] + red[1][col] + red[2][col] + red[3][col] + bsel[c0 + col];
        u2h[(size_t)g * 256 + c0 + col] = (f16)v;
    }
}

// ---- per-edge gather: feat64 = [x[row](9), x[col](9), ea(1), 0-pad], ebat = batch[row] ----
__global__ void k_gather19(int e0, int Ce,
                           const float* __restrict__ x, const float* __restrict__ eattr,
                           const int* __restrict__ ei, const int* __restrict__ batch,
                           f16* __restrict__ feat, int* __restrict__ ebat)
{
    size_t t = (size_t)blockIdx.x * 256 + threadIdx.x;
    if (t >= (size_t)Ce * 64) return;
    int i = (int)(t >> 6), j = (int)(t & 63);
    int e = e0 + i;
    float v = 0.f;
    if (j < 9)        v = x[ei[e] * 9 + j];
    else if (j < 18)  v = x[ei[E_TOTAL + e] * 9 + (j - 9)];
    else if (j == 18) v = eattr[e];
    else if (j == 19) ebat[i] = batch[ei[e]];
    feat[t] = (f16)v;
}

__global__ void k_scatter(int e0, int Ce, const f16* __restrict__ h2,
                          const int* __restrict__ ei, float* __restrict__ ssum)
{
    size_t t = (size_t)blockIdx.x * 256 + threadIdx.x;
    if (t >= (size_t)Ce * 512) return;
    int i = (int)(t >> 9), j = (int)(t & 511);
    atomicAdd(ssum + (size_t)ei[e0 + i] * 512 + j, (float)h2[t]);
}

__global__ void k_cnt(const int* __restrict__ ei, float* __restrict__ cnt)
{
    int t = blockIdx.x * 256 + threadIdx.x;
    if (t < E_TOTAL) atomicAdd(cnt + ei[t], 1.0f);
}

__global__ void k_agg(const float* __restrict__ ssum, const float* __restrict__ cnt,
                      f16* __restrict__ agg)
{
    size_t t = (size_t)blockIdx.x * 256 + threadIdx.x;
    if (t >= (size_t)NN * 512) return;
    int n = (int)(t >> 9);
    agg[t] = (f16)(ssum[t] / fmaxf(cnt[n], 1.f));
}

__global__ void k_final(const f16* __restrict__ z1, const float* __restrict__ W,
                        const float* __restrict__ b, float* __restrict__ out)
{
    int gt = blockIdx.x * 256 + threadIdx.x;
    int row = gt >> 6;
    int lane = threadIdx.x & 63;
    if (row >= NN) return;
    float s = 0.f;
#pragma unroll
    for (int c = lane; c < 512; c += 64) s += (float)z1[(size_t)row * 512 + c] * W[c];
#pragma unroll
    for (int off = 32; off; off >>= 1) s += __shfl_down(s, off);
    if (lane == 0) out[row] = s + b[0];
}

// ---------------- launch ----------------

extern "C" void kernel_launch(void* const* d_in, const int* in_sizes, int n_in,
                              void* d_out, int out_size, void* d_ws, size_t ws_size,
                              hipStream_t stream)
{
    const float* x     = (const float*)d_in[0];
    const float* eattr = (const float*)d_in[1];
    const float* u     = (const float*)d_in[2];
    const int*   ei    = (const int*)d_in[3];
    const int*   batch = (const int*)d_in[4];
    const float* Wsel  = (const float*)d_in[5];
    const float* bsel  = (const float*)d_in[6];
    const float* eW1 = (const float*)d_in[7],  * eb1 = (const float*)d_in[8];
    const float* eW2 = (const float*)d_in[9],  * eb2 = (const float*)d_in[10];
    const float* eW3 = (const float*)d_in[11], * eb3 = (const float*)d_in[12];
    const float* eW4 = (const float*)d_in[13], * eb4 = (const float*)d_in[14];
    const float* eW5 = (const float*)d_in[15], * eb5 = (const float*)d_in[16];
    const float* n1W1 = (const float*)d_in[17], * n1b1 = (const float*)d_in[18];
    const float* n1W2 = (const float*)d_in[19], * n1b2 = (const float*)d_in[20];
    const float* n2W1 = (const float*)d_in[21], * n2b1 = (const float*)d_in[22];
    const float* n2W2 = (const float*)d_in[23], * n2b2 = (const float*)d_in[24];
    float* out = (float*)d_out;

    char* ws = (char*)d_ws;
    size_t off = 0;
    auto alc = [&](size_t bytes) { char* p = ws + off; off += (bytes + 255) & ~(size_t)255; return p; };

    float* ssum  = (float*)alc((size_t)NN * 512 * 4);
    float* cnt   = (float*)alc((size_t)NN * 4);
    float* zbias = (float*)alc(1024 * 4);
    f16* u2h     = (f16*)alc((size_t)128 * 256 * 2);      // 64 valid rows, pad for GEMM reads
    f16* ubias_e = (f16*)alc((size_t)64 * 1024 * 2);
    f16* ubias_n = (f16*)alc((size_t)64 * 512 * 2);
    f16* eW1t19  = (f16*)alc((size_t)1024 * 64 * 2);
    f16* eW1ut   = (f16*)alc((size_t)1024 * 256 * 2);
    f16* eW2t    = (f16*)alc((size_t)1024 * 1024 * 2);
    f16* eW3t    = (f16*)alc((size_t)1024 * 1024 * 2);
    f16* eW4t    = (f16*)alc((size_t)1024 * 1024 * 2);
    f16* eW5t    = (f16*)alc((size_t)512 * 1024 * 2);
    f16* n1W1et  = (f16*)alc((size_t)512 * 512 * 2);
    f16* n1W2t   = (f16*)alc((size_t)512 * 512 * 2);
    f16* n2W1et  = (f16*)alc((size_t)512 * 512 * 2);
    f16* n2W1ut  = (f16*)alc((size_t)512 * 256 * 2);
    f16* agg     = (f16*)alc((size_t)20096 * 512 * 2);
    f16* z1      = (f16*)alc((size_t)20096 * 512 * 2);
    size_t fixed = off;

    // chunk region: per-edge = feat64 (128B) + buf1 (2048B) + buf2 (2048B) + ebat (4B)
    size_t per_edge = 64 * 2 + 1024 * 2 + 1024 * 2 + 4;
    size_t avail = ws_size > fixed ? ws_size - fixed : 0;
    long long Cll = (long long)(avail / per_edge);
    int C = (int)((Cll / 128) * 128);
    if (C > E_TOTAL) C = E_TOTAL;
    if (C < 128) C = 128;

    f16* featc = (f16*)(ws + fixed);
    f16* buf1  = featc + (size_t)C * 64;
    f16* buf2  = buf1 + (size_t)C * 1024;
    int* ebat  = (int*)(buf2 + (size_t)C * 1024);

    // zero ssum, cnt, zbias (contiguous)
    size_t zlen = (size_t)((char*)zbias - (char*)ssum) + 1024 * 4;
    hipMemsetAsync(ssum, 0, zlen, stream);

    auto wt = [&](const float* W, f16* Wt, int r0, int Ksub, int N, int Kp) {
        size_t tot = (size_t)N * Kp;
        k_wt<<<(unsigned)((tot + 255) / 256), 256, 0, stream>>>(W, Wt, r0, Ksub, N, Kp);
    };
    wt(eW1, eW1t19, 0, 19, 1024, 64);
    wt(eW1, eW1ut, 19, 256, 1024, 256);
    wt(eW2, eW2t, 0, 1024, 1024, 1024);
    wt(eW3, eW3t, 0, 1024, 1024, 1024);
    wt(eW4, eW4t, 0, 1024, 1024, 1024);
    wt(eW5, eW5t, 0, 1024, 512, 1024);
    wt(n1W1, n1W1et, 9, 512, 512, 512);
    wt(n1W2, n1W2t, 0, 512, 512, 512);
    wt(n2W1, n2W1et, 9, 512, 512, 512);
    wt(n2W1, n2W1ut, 521, 256, 512, 256);

    k_u2<<<dim3(4, NGRAPH), 256, 0, stream>>>(u, Wsel, bsel, u2h);
    k_cnt<<<(E_TOTAL + 255) / 256, 256, 0, stream>>>(ei, cnt);

    // u-contribution tables (include the layer bias)
    hgemm<0,0,0><<<dim3(8, 1), 256, 0, stream>>>(64, 1024, 256, u2h, 256, eW1ut,
        ubias_e, 1024, eb1, nullptr, nullptr, nullptr, nullptr, nullptr);
    hgemm<0,0,0><<<dim3(4, 1), 256, 0, stream>>>(64, 512, 256, u2h, 256, n2W1ut,
        ubias_n, 512, n2b1, nullptr, nullptr, nullptr, nullptr, nullptr);

    for (int e0 = 0; e0 < E_TOTAL; e0 += C) {
        int Ce = E_TOTAL - e0 < C ? E_TOTAL - e0 : C;
        int gy = (Ce + 127) / 128;

        k_gather19<<<(unsigned)(((size_t)Ce * 64 + 255) / 256), 256, 0, stream>>>(
            e0, Ce, x, eattr, ei, batch, featc, ebat);

        hgemm<1,1,0><<<dim3(8, gy), 256, 0, stream>>>(Ce, 1024, 64, featc, 64, eW1t19,
            buf1, 1024, zbias, ubias_e, ebat, nullptr, nullptr, nullptr);
        hgemm<1,0,0><<<dim3(8, gy), 256, 0, stream>>>(Ce, 1024, 1024, buf1, 1024, eW2t,
            buf2, 1024, eb2, nullptr, nullptr, nullptr, nullptr, nullptr);
        hgemm<1,0,0><<<dim3(8, gy), 256, 0, stream>>>(Ce, 1024, 1024, buf2, 1024, eW3t,
            buf1, 1024, eb3, nullptr, nullptr, nullptr, nullptr, nullptr);
        hgemm<1,0,0><<<dim3(8, gy), 256, 0, stream>>>(Ce, 1024, 1024, buf1, 1024, eW4t,
            buf2, 1024, eb4, nullptr, nullptr, nullptr, nullptr, nullptr);
        hgemm<0,0,0><<<dim3(4, gy), 256, 0, stream>>>(Ce, 512, 1024, buf2, 1024, eW5t,
            buf1, 512, eb5, nullptr, nullptr, nullptr, nullptr, nullptr);   // e -> buf1

        hgemm<1,0,1><<<dim3(4, gy), 256, 0, stream>>>(Ce, 512, 512, buf1, 512, n1W1et,
            buf2, 512, n1b1, nullptr, nullptr, x, ei + E_TOTAL + e0, n1W1);  // h1 -> buf2
        hgemm<1,0,0><<<dim3(4, gy), 256, 0, stream>>>(Ce, 512, 512, buf2, 512, n1W2t,
            buf1, 512, n1b2, nullptr, nullptr, nullptr, nullptr, nullptr);   // h2 -> buf1

        k_scatter<<<(unsigned)(((size_t)Ce * 512 + 255) / 256), 256, 0, stream>>>(
            e0, Ce, buf1, ei, ssum);
    }

    // readout
    k_agg<<<(unsigned)(((size_t)NN * 512 + 255) / 256), 256, 0, stream>>>(ssum, cnt, agg);
    hgemm<1,1,1><<<dim3(4, 157), 256, 0, stream>>>(NN, 512, 512, agg, 512, n2W1et,
        z1, 512, zbias, ubias_n, batch, x, nullptr, n2W1);
    k_final<<<(NN * 64 + 255) / 256, 256, 0, stream>>>(z1, n2W2, n2b2, out);
}